// Round 1
// baseline (3210.367 us; speedup 1.0000x reference)
//
#include <hip/hip_runtime.h>

#define BSZ 200000
#define NSTEPS 10
#define TOLFUN_C 1e-6f
#define ALPHA_C 1e-4f

// ---------------- ws layout (float elements) ----------------
// Per-sample: y[8], yold[8], F[8], dy[8], sj[8] (sech^2 at jac point),
//             fold, slope, resnorm, f2, trial_rn, trial_fobj
// Then reduction slot area (uint32). Total ~36.8 MB.
#define OFF_Y     ((size_t)0)
#define OFF_YOLD  ((size_t)BSZ*8)
#define OFF_F     ((size_t)BSZ*16)
#define OFF_DY    ((size_t)BSZ*24)
#define OFF_SJ    ((size_t)BSZ*32)
#define OFF_FOLD  ((size_t)BSZ*40)
#define OFF_SLOPE ((size_t)BSZ*41)
#define OFF_RESN  ((size_t)BSZ*42)
#define OFF_F2    ((size_t)BSZ*43)
#define OFF_TRN   ((size_t)BSZ*44)
#define OFF_TFO   ((size_t)BSZ*45)
#define OFF_R     ((size_t)BSZ*46)
#define R_SLOTS   (2 + NSTEPS*13)
// R[0]=max(rn0) key, R[1]=max(rn0/(100*rn0)) key
// per step k (0-indexed), base 2+k*13:
//  +0 gmax(maxkey) +1 anyNFdy +2 anyArmijo +3 minQuad(minkey) +4 anyAnot0
//  +5 anyDiscNeg +6 anyBle0 +7 minX(minkey) +8 minZ(minkey) +9 minW(minkey)
//  +10 anyNanF +11 maxTRN(maxkey) +12 maxRatio(maxkey)
#define KEY_MAX_IDENT 0x007FFFFFu  /* fkey(-inf) */
#define KEY_MIN_IDENT 0xFF800000u  /* fkey(+inf) */

static __device__ __forceinline__ float nanmax2(float a, float b){
    return (__builtin_isnan(a) || __builtin_isnan(b)) ? __builtin_nanf("") : fmaxf(a, b);
}
static __device__ __forceinline__ float nanmin2(float a, float b){
    return (__builtin_isnan(a) || __builtin_isnan(b)) ? __builtin_nanf("") : fminf(a, b);
}
static __device__ __forceinline__ float safe_div(float n, float d){
    return (fabsf(d) > 1e-30f) ? (n / d) : 0.0f;   // matches jnp _safe_div incl. NaN denom -> 0
}
// monotone float->uint key (works with atomicMax/Min on unsigned)
static __device__ __forceinline__ unsigned fkey(float x){
    unsigned u = __float_as_uint(x);
    return (u & 0x80000000u) ? ~u : (u | 0x80000000u);
}
static __device__ __forceinline__ float funkey(unsigned u){
    return (u & 0x80000000u) ? __uint_as_float(u & 0x7FFFFFFFu) : __uint_as_float(~u);
}
static __device__ __forceinline__ unsigned fkey_max(float x){
    if (__builtin_isnan(x)) x = __uint_as_float(0x7FC00000u); // +NaN: dominates max
    return fkey(x);
}
static __device__ __forceinline__ unsigned fkey_min(float x){
    if (__builtin_isnan(x)) x = __uint_as_float(0xFFC00000u); // -NaN: dominates min
    return fkey(x);
}
static __device__ __forceinline__ void ld8(const float* p, float* v){
    float4 a = ((const float4*)p)[0], b = ((const float4*)p)[1];
    v[0]=a.x; v[1]=a.y; v[2]=a.z; v[3]=a.w; v[4]=b.x; v[5]=b.y; v[6]=b.z; v[7]=b.w;
}
static __device__ __forceinline__ void st8(float* p, const float* v){
    float4 a, b;
    a.x=v[0]; a.y=v[1]; a.z=v[2]; a.w=v[3];
    b.x=v[4]; b.y=v[5]; b.z=v[6]; b.w=v[7];
    ((float4*)p)[0]=a; ((float4*)p)[1]=b;
}

struct ScalarState {
    float lam, lam1, lam2, lam_min, maxrn, ratmax;
    int   niter, exitflag;
    bool  upd_prev, cont_prev;
};

// Deterministically replay the global scalar control chain from the stored
// per-step reduction slots. Every thread does this redundantly (all loads are
// wave-uniform -> scalar cache). nsteps_done = number of fully finished steps.
static __device__ ScalarState replay(const unsigned* R, int nsteps_done){
    ScalarState s;
    s.lam = 1.0f; s.lam1 = 1.0f; s.lam2 = 0.5f; s.lam_min = 0.0f;
    s.maxrn  = funkey(R[0]);
    s.ratmax = funkey(R[1]);
    s.niter = 0; s.exitflag = 1;
    s.upd_prev = false; s.cont_prev = false;
    for (int j = 0; j < nsteps_done; ++j){
        const unsigned* r = R + 2 + j*13;
        bool active    = ((s.maxrn > TOLFUN_C) || (s.lam < 1.0f)) && (s.exitflag >= 0) && (s.niter <= 1000);
        bool is_newton = (s.lam == 1.0f);
        float lam_min_new = is_newton ? safe_div(1e-12f, funkey(r[0])) : s.lam_min;
        bool brk = (s.lam < lam_min_new);
        bool bad = is_newton ? (r[1] != 0u) : false;
        bool upd = active && !brk && !bad;
        int niter_new = active ? (is_newton ? s.niter + 1 : s.niter) : s.niter;
        int ef_new = s.exitflag;
        if (active && brk) ef_new = 2;
        else if (active && !brk && bad) ef_new = -1;
        bool cont = false;
        if (upd){
            float lam1c = s.lam;
            bool backtrack = (r[2] != 0u);
            float lamq  = funkey(r[3]);
            bool allA0  = (r[4] == 0u);
            bool anyDN  = (r[5] != 0u);
            bool anyB0  = (r[6] != 0u);
            float lam_tmp_min = allA0 ? funkey(r[7])
                              : (anyDN ? (0.5f*lam1c)
                              : (anyB0 ? funkey(r[8]) : funkey(r[9])));
            float lam_cubic = nanmin2(lam_tmp_min, 0.5f*lam1c);
            float lam_bt = (s.lam == 1.0f) ? lamq : lam_cubic;
            bool nanf = (r[10] != 0u);
            float lam_new = backtrack ? lam_bt : (nanf ? 0.5f*lam1c : 1.0f);
            cont = (lam_new < 1.0f);
            float lam2_new = cont ? lam1c : s.lam2;
            if (cont) lam_new = nanmax2(lam_new, 0.1f*lam1c);
            float maxrn_new  = cont ? s.maxrn  : funkey(r[11]);
            float ratmax_new = cont ? s.ratmax : funkey(r[12]);
            s.lam = lam_new; s.lam1 = lam1c; s.lam2 = lam2_new;
            s.lam_min = lam_min_new; s.maxrn = maxrn_new; s.ratmax = ratmax_new;
        }
        s.niter = niter_new; s.exitflag = ef_new;
        s.upd_prev = upd; s.cont_prev = cont;
    }
    return s;
}

// -------- init reduction slots to identities (d_ws is poisoned 0xAA) --------
__global__ void kPre(unsigned* __restrict__ R){
    int i = threadIdx.x;
    if (i >= R_SLOTS) return;
    unsigned v;
    if (i < 2) v = KEY_MAX_IDENT;
    else {
        int off = (i - 2) % 13;
        bool ismin = (off==3 || off==7 || off==8 || off==9);
        bool ismax = (off==0 || off==11 || off==12);
        v = ismin ? KEY_MIN_IDENT : (ismax ? KEY_MAX_IDENT : 0u);
    }
    R[i] = v;
}

// -------- state0: F0=err(y0), jac0 (as sj), rn0, fobj0 --------
__global__ __launch_bounds__(256) void kInit(
    const float* __restrict__ y0g, const float* __restrict__ Wm, const float* __restrict__ Vm,
    const float* __restrict__ dtp, const float* __restrict__ tp, float* __restrict__ ws)
{
    __shared__ float sW[64], sV[64];
    int t = threadIdx.x;
    if (t < 64) sW[t] = Wm[t];
    else if (t < 128) sV[t-64] = Vm[t-64];
    __syncthreads();
    unsigned* R = (unsigned*)(ws + OFF_R);
    int tid = blockIdx.x*256 + t;
    bool valid = tid < BSZ;
    float c0 = 0.01f * sinf(*tp);
    float rn = -__builtin_inff(), ratio = -__builtin_inff();
    if (valid){
        float y[8]; ld8(y0g + (size_t)tid*8, y);
        float u[8], z[8], sj[8];
        #pragma unroll
        for (int k=0;k<8;k++){
            float acc = 0.f;
            #pragma unroll
            for (int m=0;m<8;m++) acc += y[m]*sW[m*8+k];
            u[k]=acc;
        }
        #pragma unroll
        for (int k=0;k<8;k++){ z[k]=tanhf(u[k]); sj[k]=1.0f - z[k]*z[k]; }
        float Fn[8];
        #pragma unroll
        for (int i=0;i<8;i++){
            float tv = 0.f;
            #pragma unroll
            for (int k=0;k<8;k++) tv += z[k]*sV[k*8+i];
            Fn[i] = 0.0f - ((tv - 0.1f*y[i]) + c0);   // (y0-y0)/dt == 0
        }
        float fold = 0.f;
        #pragma unroll
        for (int i=0;i<8;i++) fold += Fn[i]*Fn[i];
        float rn0 = fabsf(Fn[0]);
        #pragma unroll
        for (int i=1;i<8;i++) rn0 = nanmax2(rn0, fabsf(Fn[i]));
        float zero8[8] = {0,0,0,0,0,0,0,0};
        st8(ws+OFF_Y   +(size_t)tid*8, y);
        st8(ws+OFF_YOLD+(size_t)tid*8, y);
        st8(ws+OFF_F   +(size_t)tid*8, Fn);
        st8(ws+OFF_DY  +(size_t)tid*8, zero8);
        st8(ws+OFF_SJ  +(size_t)tid*8, sj);
        ws[OFF_FOLD+tid]=fold; ws[OFF_SLOPE+tid]=0.0f;
        ws[OFF_RESN+tid]=rn0;  ws[OFF_F2+tid]=fold;
        ws[OFF_TRN+tid]=0.0f;  ws[OFF_TFO+tid]=0.0f;
        rn = rn0;
        ratio = safe_div(rn0, 100.0f*rn0);   // resnorm0 = 100*rn0
    }
    #pragma unroll
    for (int o=32;o>=1;o>>=1){
        rn    = nanmax2(rn,    __shfl_xor(rn,    o, 64));
        ratio = nanmax2(ratio, __shfl_xor(ratio, o, 64));
    }
    if ((t & 63) == 0){
        atomicMax(&R[0], fkey_max(rn));
        atomicMax(&R[1], fkey_max(ratio));
    }
}

// -------- phase A: Newton direction (jac select, solve, slope, fold, lam_min input) --------
__global__ __launch_bounds__(256) void phaseA(
    const float* __restrict__ Wm, const float* __restrict__ Vm,
    const float* __restrict__ dtp, float* __restrict__ ws, int step)
{
    __shared__ float sW[64], sV[64];
    int t = threadIdx.x;
    if (t < 64) sW[t] = Wm[t];
    else if (t < 128) sV[t-64] = Vm[t-64];
    __syncthreads();

    unsigned* R = (unsigned*)(ws + OFF_R);
    ScalarState S = replay(R, step-1);
    bool active    = ((S.maxrn > TOLFUN_C) || (S.lam < 1.0f)) && (S.exitflag >= 0) && (S.niter <= 1000);
    bool is_newton = (S.lam == 1.0f);
    if (!active || !is_newton) return;   // uniform
    bool recompute = (S.ratmax > 0.2f);

    int tid = blockIdx.x*256 + t;
    bool valid = tid < BSZ;
    float invdt = 1.0f / (*dtp);
    float gml = -__builtin_inff();
    bool nf = false;

    if (valid){
        float y[8], Fv[8], sj[8];
        ld8(ws+OFF_Y+(size_t)tid*8, y);
        ld8(ws+OFF_F+(size_t)tid*8, Fv);
        if (recompute){
            float u[8];
            #pragma unroll
            for (int k=0;k<8;k++){
                float acc = 0.f;
                #pragma unroll
                for (int m=0;m<8;m++) acc += y[m]*sW[m*8+k];
                u[k]=acc;
            }
            #pragma unroll
            for (int k=0;k<8;k++){ float z = tanhf(u[k]); sj[k] = 1.0f - z*z; }
            st8(ws+OFF_SJ+(size_t)tid*8, sj);   // eager commit (safe: upd-false => frozen forever)
        } else {
            ld8(ws+OFF_SJ+(size_t)tid*8, sj);
        }
        // J[i][j] = d err_i / d y_j = delta/dt - ( sum_k (W[j,k]*s_k) V[k,i] - 0.1*delta )
        float J[8][8];
        #pragma unroll
        for (int j=0;j<8;j++){
            float zj[8];
            #pragma unroll
            for (int k=0;k<8;k++) zj[k] = sW[j*8+k]*sj[k];
            #pragma unroll
            for (int i=0;i<8;i++){
                float acc = 0.f;
                #pragma unroll
                for (int k=0;k<8;k++) acc += zj[k]*sV[k*8+i];
                J[i][j] = (i==j) ? (invdt - (acc - 0.1f)) : (0.0f - acc);
            }
        }
        float fold = 0.f;
        #pragma unroll
        for (int i=0;i<8;i++) fold += Fv[i]*Fv[i];
        float gv[8];
        #pragma unroll
        for (int j=0;j<8;j++){
            float acc = 0.f;
            #pragma unroll
            for (int i=0;i<8;i++) acc += Fv[i]*J[i][j];
            gv[j]=acc;
        }
        // solve J x = F (no-pivot GE; J is strongly diagonally dominant: diag ~10.1, offdiag <~0.3)
        float x[8];
        #pragma unroll
        for (int i=0;i<8;i++) x[i]=Fv[i];
        #pragma unroll
        for (int c=0;c<8;c++){
            float ip = 1.0f / J[c][c];
            #pragma unroll
            for (int r2=c+1;r2<8;r2++){
                float m = J[r2][c]*ip;
                #pragma unroll
                for (int jj=c+1;jj<8;jj++) J[r2][jj] -= m*J[c][jj];
                x[r2] -= m*x[c];
            }
        }
        float wv[8];
        #pragma unroll
        for (int c=7;c>=0;c--){
            float acc = x[c];
            #pragma unroll
            for (int jj=c+1;jj<8;jj++) acc -= J[c][jj]*wv[jj];
            wv[c] = acc / J[c][c];
        }
        float dy[8];
        #pragma unroll
        for (int i=0;i<8;i++) dy[i] = -wv[i];
        float slope = 0.f;
        #pragma unroll
        for (int j=0;j<8;j++) slope += gv[j]*dy[j];
        st8(ws+OFF_DY  +(size_t)tid*8, dy);
        st8(ws+OFF_YOLD+(size_t)tid*8, y);
        ws[OFF_FOLD+tid]  = fold;
        ws[OFF_SLOPE+tid] = slope;
        #pragma unroll
        for (int i=0;i<8;i++){
            float rr = fabsf(dy[i]) / nanmax2(fabsf(y[i]), 1.0f);
            gml = nanmax2(gml, rr);
            nf = nf || !__builtin_isfinite(dy[i]);
        }
    }
    #pragma unroll
    for (int o=32;o>=1;o>>=1) gml = nanmax2(gml, __shfl_xor(gml, o, 64));
    unsigned long long anym = __ballot(nf ? 1 : 0);
    if ((t & 63) == 0){
        unsigned* r1 = R + 2 + (step-1)*13;
        atomicMax(&r1[0], fkey_max(gml));
        if (anym) atomicOr(&r1[1], 1u);
    }
}

// -------- phase B: trial step + line-search reductions + commits --------
__global__ __launch_bounds__(256) void phaseB(
    const float* __restrict__ y0g, const float* __restrict__ Wm, const float* __restrict__ Vm,
    const float* __restrict__ dtp, const float* __restrict__ tp,
    float* __restrict__ ws, int step)
{
    __shared__ float sW[64], sV[64];
    int t = threadIdx.x;
    if (t < 64) sW[t] = Wm[t];
    else if (t < 128) sV[t-64] = Vm[t-64];
    __syncthreads();

    unsigned* R = (unsigned*)(ws + OFF_R);
    ScalarState S = replay(R, step-1);
    bool active    = ((S.maxrn > TOLFUN_C) || (S.lam < 1.0f)) && (S.exitflag >= 0) && (S.niter <= 1000);
    bool is_newton = (S.lam == 1.0f);
    unsigned* r = R + 2 + (step-1)*13;
    float lam_min_new = is_newton ? safe_div(1e-12f, funkey(r[0])) : S.lam_min;
    bool brk = (S.lam < lam_min_new);
    bool bad = is_newton ? (r[1] != 0u) : false;
    bool upd = active && !brk && !bad;
    if (!upd) return;   // uniform; upd-false is permanent => nothing below ever matters again

    int tid = blockIdx.x*256 + t;
    bool valid = tid < BSZ;
    float dt = *dtp;
    float c0 = 0.01f * sinf(*tp);
    float lam = S.lam, lam2 = S.lam2;

    bool armijo=false, aNot0=false, dN=false, ble=false, nanf=false;
    float lq = __builtin_inff(), mX = __builtin_inff(), mZ = __builtin_inff(), mW = __builtin_inff();
    float trn = -__builtin_inff(), ratio = -__builtin_inff();

    if (valid){
        // lazy commits from previous step (f2 / resnorm depend on prev cont)
        float f2v   = ws[OFF_F2+tid];
        float rnold = ws[OFF_RESN+tid];
        if (S.upd_prev){
            if (S.cont_prev){ f2v = ws[OFF_TFO+tid]; ws[OFF_F2+tid] = f2v; }
            else            { rnold = ws[OFF_TRN+tid]; ws[OFF_RESN+tid] = rnold; }
        }
        float foldv  = ws[OFF_FOLD+tid];
        float slopev = ws[OFF_SLOPE+tid];
        float yold[8], dyv[8];
        ld8(ws+OFF_YOLD+(size_t)tid*8, yold);
        ld8(ws+OFF_DY  +(size_t)tid*8, dyv);
        float yn[8];
        #pragma unroll
        for (int i=0;i<8;i++) yn[i] = yold[i] + dyv[i]*lam;
        float u[8], z[8];
        #pragma unroll
        for (int k=0;k<8;k++){
            float acc = 0.f;
            #pragma unroll
            for (int m=0;m<8;m++) acc += yn[m]*sW[m*8+k];
            u[k]=acc;
        }
        #pragma unroll
        for (int k=0;k<8;k++) z[k] = tanhf(u[k]);
        float Fn[8];
        #pragma unroll
        for (int i=0;i<8;i++){
            float tv = 0.f;
            #pragma unroll
            for (int k=0;k<8;k++) tv += z[k]*sV[k*8+i];
            Fn[i] = (yn[i] - y0g[(size_t)tid*8+i])/dt - ((tv - 0.1f*yn[i]) + c0);
        }
        float f_obj = 0.f;
        #pragma unroll
        for (int i=0;i<8;i++) f_obj += Fn[i]*Fn[i];
        // commit y, F (gated only by upd, which is true here)
        st8(ws+OFF_Y+(size_t)tid*8, yn);
        st8(ws+OFF_F+(size_t)tid*8, Fn);
        float rn = fabsf(Fn[0]);
        #pragma unroll
        for (int i=1;i<8;i++) rn = nanmax2(rn, fabsf(Fn[i]));
        ws[OFF_TRN+tid] = rn;
        ws[OFF_TFO+tid] = f_obj;

        armijo = f_obj > (foldv + (ALPHA_C*lam)*slopev);
        lq = safe_div((-slopev)*0.5f, (f_obj - foldv) - slopev);
        float lam1v = lam;
        float Af = safe_div(1.0f, lam1v - lam2);
        float i1 = safe_div(1.0f, lam1v*lam1v);
        float i2 = safe_div(1.0f, lam2*lam2);
        float Cc0 = (f_obj - foldv) - lam1v*slopev;
        float Cc1 = (f2v  - foldv) - lam2 *slopev;
        float av = Af*(i1*Cc0 - i2*Cc1);
        float bv = Af*((-(lam2*i1))*Cc0 + (lam1v*i2)*Cc1);
        float disc = bv*bv - (3.0f*av)*slopev;
        float dm = __builtin_isnan(disc) ? disc : fmaxf(disc, 0.0f);  // jnp.maximum NaN-prop
        float sq = sqrtf(dm);
        aNot0 = (av != 0.0f);
        dN    = (disc < 0.0f);
        ble   = (bv <= 0.0f);
        mX = safe_div(-slopev, 2.0f*bv);
        mZ = safe_div(-bv + sq, 3.0f*av);
        mW = safe_div(-slopev, bv + sq);
        nanf = !__builtin_isfinite(f_obj);
        trn = rn;
        ratio = safe_div(rn, rnold);   // resnorm_new / resnorm0_new candidate (cont=false case)
    }
    #pragma unroll
    for (int o=32;o>=1;o>>=1){
        lq    = nanmin2(lq,    __shfl_xor(lq,    o, 64));
        mX    = nanmin2(mX,    __shfl_xor(mX,    o, 64));
        mZ    = nanmin2(mZ,    __shfl_xor(mZ,    o, 64));
        mW    = nanmin2(mW,    __shfl_xor(mW,    o, 64));
        trn   = nanmax2(trn,   __shfl_xor(trn,   o, 64));
        ratio = nanmax2(ratio, __shfl_xor(ratio, o, 64));
    }
    unsigned long long bArm = __ballot(armijo ? 1 : 0);
    unsigned long long bA0  = __ballot(aNot0  ? 1 : 0);
    unsigned long long bDN  = __ballot(dN     ? 1 : 0);
    unsigned long long bB0  = __ballot(ble    ? 1 : 0);
    unsigned long long bNF  = __ballot(nanf   ? 1 : 0);
    if ((t & 63) == 0){
        if (bArm) atomicOr(&r[2], 1u);
        atomicMin(&r[3], fkey_min(lq));
        if (bA0)  atomicOr(&r[4], 1u);
        if (bDN)  atomicOr(&r[5], 1u);
        if (bB0)  atomicOr(&r[6], 1u);
        atomicMin(&r[7], fkey_min(mX));
        atomicMin(&r[8], fkey_min(mZ));
        atomicMin(&r[9], fkey_min(mW));
        if (bNF)  atomicOr(&r[10], 1u);
        atomicMax(&r[11], fkey_max(trn));
        atomicMax(&r[12], fkey_max(ratio));
    }
}

// -------- output: y, F, exitflag --------
__global__ __launch_bounds__(256) void kOut(const float* __restrict__ ws, float* __restrict__ out)
{
    const unsigned* R = (const unsigned*)(ws + OFF_R);
    ScalarState S = replay(R, NSTEPS);
    int tid = blockIdx.x*256 + threadIdx.x;
    if (tid < BSZ){
        float v[8];
        ld8(ws+OFF_Y+(size_t)tid*8, v);
        st8(out + (size_t)tid*8, v);
        ld8(ws+OFF_F+(size_t)tid*8, v);
        st8(out + (size_t)BSZ*8 + (size_t)tid*8, v);
    }
    if (tid == 0) out[(size_t)BSZ*16] = (float)S.exitflag;
}

extern "C" void kernel_launch(void* const* d_in, const int* in_sizes, int n_in,
                              void* d_out, int out_size, void* d_ws, size_t ws_size,
                              hipStream_t stream)
{
    const float* y0g = (const float*)d_in[0];
    const float* dtp = (const float*)d_in[1];
    const float* tp  = (const float*)d_in[2];
    const float* Wm  = (const float*)d_in[3];
    const float* Vm  = (const float*)d_in[4];
    float* ws  = (float*)d_ws;
    float* out = (float*)d_out;
    dim3 grid((BSZ + 255)/256), blk(256);

    hipLaunchKernelGGL(kPre, dim3(1), dim3(256), 0, stream, (unsigned*)(ws + OFF_R));
    hipLaunchKernelGGL(kInit, grid, blk, 0, stream, y0g, Wm, Vm, dtp, tp, ws);
    for (int s = 1; s <= NSTEPS; ++s){
        hipLaunchKernelGGL(phaseA, grid, blk, 0, stream, Wm, Vm, dtp, ws, s);
        hipLaunchKernelGGL(phaseB, grid, blk, 0, stream, y0g, Wm, Vm, dtp, tp, ws, s);
    }
    hipLaunchKernelGGL(kOut, grid, blk, 0, stream, ws, out);
}

// Round 2
// 772.937 us; speedup vs baseline: 4.1535x; 4.1535x over previous
//
#include <hip/hip_runtime.h>

#define BSZ 200000
#define NSTEPS 10
#define TOLFUN_C 1e-6f
#define ALPHA_C 1e-4f

// ---------------- ws layout (float elements) ----------------
#define OFF_Y     ((size_t)0)
#define OFF_YOLD  ((size_t)BSZ*8)
#define OFF_F     ((size_t)BSZ*16)
#define OFF_DY    ((size_t)BSZ*24)
#define OFF_SJ    ((size_t)BSZ*32)
#define OFF_FOLD  ((size_t)BSZ*40)
#define OFF_SLOPE ((size_t)BSZ*41)
#define OFF_RESN  ((size_t)BSZ*42)
#define OFF_F2    ((size_t)BSZ*43)
#define OFF_TRN   ((size_t)BSZ*44)
#define OFF_TFO   ((size_t)BSZ*45)
#define OFF_R     ((size_t)BSZ*46)
#define R_SLOTS   (2 + NSTEPS*13)
// R[0]=max(rn0) key, R[1]=max(rn0/(100*rn0)) key
// per step k (0-indexed), base 2+k*13:
//  +0 gmax(maxkey) +1 anyNFdy +2 anyArmijo +3 minQuad(minkey) +4 anyAnot0
//  +5 anyDiscNeg +6 anyBle0 +7 minX(minkey) +8 minZ(minkey) +9 minW(minkey)
//  +10 anyNanF +11 maxTRN(maxkey) +12 maxRatio(maxkey)
#define KEY_MAX_IDENT 0x007FFFFFu  /* fkey(-inf) */
#define KEY_MIN_IDENT 0xFF800000u  /* fkey(+inf) */

static __device__ __forceinline__ float nanmax2(float a, float b){
    return (__builtin_isnan(a) || __builtin_isnan(b)) ? __builtin_nanf("") : fmaxf(a, b);
}
static __device__ __forceinline__ float nanmin2(float a, float b){
    return (__builtin_isnan(a) || __builtin_isnan(b)) ? __builtin_nanf("") : fminf(a, b);
}
static __device__ __forceinline__ float safe_div(float n, float d){
    return (fabsf(d) > 1e-30f) ? (n / d) : 0.0f;   // matches jnp _safe_div incl. NaN denom -> 0
}
// monotone float->uint key (works with atomicMax/Min on unsigned)
static __device__ __forceinline__ unsigned fkey(float x){
    unsigned u = __float_as_uint(x);
    return (u & 0x80000000u) ? ~u : (u | 0x80000000u);
}
static __device__ __forceinline__ float funkey(unsigned u){
    return (u & 0x80000000u) ? __uint_as_float(u & 0x7FFFFFFFu) : __uint_as_float(~u);
}
static __device__ __forceinline__ unsigned fkey_max(float x){
    if (__builtin_isnan(x)) x = __uint_as_float(0x7FC00000u); // +NaN: dominates max
    return fkey(x);
}
static __device__ __forceinline__ unsigned fkey_min(float x){
    if (__builtin_isnan(x)) x = __uint_as_float(0xFFC00000u); // -NaN: dominates min
    return fkey(x);
}
static __device__ __forceinline__ void ld8(const float* p, float* v){
    float4 a = ((const float4*)p)[0], b = ((const float4*)p)[1];
    v[0]=a.x; v[1]=a.y; v[2]=a.z; v[3]=a.w; v[4]=b.x; v[5]=b.y; v[6]=b.z; v[7]=b.w;
}
static __device__ __forceinline__ void st8(float* p, const float* v){
    float4 a, b;
    a.x=v[0]; a.y=v[1]; a.z=v[2]; a.w=v[3];
    b.x=v[4]; b.y=v[5]; b.z=v[6]; b.w=v[7];
    ((float4*)p)[0]=a; ((float4*)p)[1]=b;
}

struct ScalarState {
    float lam, lam1, lam2, lam_min, maxrn, ratmax;
    int   niter, exitflag;
    bool  upd_prev, cont_prev;
};

// Deterministically replay the global scalar control chain from the stored
// per-step reduction slots. Every thread does this redundantly.
static __device__ ScalarState replay(const unsigned* R, int nsteps_done){
    ScalarState s;
    s.lam = 1.0f; s.lam1 = 1.0f; s.lam2 = 0.5f; s.lam_min = 0.0f;
    s.maxrn  = funkey(R[0]);
    s.ratmax = funkey(R[1]);
    s.niter = 0; s.exitflag = 1;
    s.upd_prev = false; s.cont_prev = false;
    for (int j = 0; j < nsteps_done; ++j){
        const unsigned* r = R + 2 + j*13;
        bool active    = ((s.maxrn > TOLFUN_C) || (s.lam < 1.0f)) && (s.exitflag >= 0) && (s.niter <= 1000);
        bool is_newton = (s.lam == 1.0f);
        float lam_min_new = is_newton ? safe_div(1e-12f, funkey(r[0])) : s.lam_min;
        bool brk = (s.lam < lam_min_new);
        bool bad = is_newton ? (r[1] != 0u) : false;
        bool upd = active && !brk && !bad;
        int niter_new = active ? (is_newton ? s.niter + 1 : s.niter) : s.niter;
        int ef_new = s.exitflag;
        if (active && brk) ef_new = 2;
        else if (active && !brk && bad) ef_new = -1;
        bool cont = false;
        if (upd){
            float lam1c = s.lam;
            bool backtrack = (r[2] != 0u);
            float lamq  = funkey(r[3]);
            bool allA0  = (r[4] == 0u);
            bool anyDN  = (r[5] != 0u);
            bool anyB0  = (r[6] != 0u);
            float lam_tmp_min = allA0 ? funkey(r[7])
                              : (anyDN ? (0.5f*lam1c)
                              : (anyB0 ? funkey(r[8]) : funkey(r[9])));
            float lam_cubic = nanmin2(lam_tmp_min, 0.5f*lam1c);
            float lam_bt = (s.lam == 1.0f) ? lamq : lam_cubic;
            bool nanf = (r[10] != 0u);
            float lam_new = backtrack ? lam_bt : (nanf ? 0.5f*lam1c : 1.0f);
            cont = (lam_new < 1.0f);
            float lam2_new = cont ? lam1c : s.lam2;
            if (cont) lam_new = nanmax2(lam_new, 0.1f*lam1c);
            float maxrn_new  = cont ? s.maxrn  : funkey(r[11]);
            float ratmax_new = cont ? s.ratmax : funkey(r[12]);
            s.lam = lam_new; s.lam1 = lam1c; s.lam2 = lam2_new;
            s.lam_min = lam_min_new; s.maxrn = maxrn_new; s.ratmax = ratmax_new;
        }
        s.niter = niter_new; s.exitflag = ef_new;
        s.upd_prev = upd; s.cont_prev = cont;
    }
    return s;
}

// -------- init reduction slots to identities (d_ws is poisoned 0xAA) --------
__global__ void kPre(unsigned* __restrict__ R){
    int i = threadIdx.x;
    if (i >= R_SLOTS) return;
    unsigned v;
    if (i < 2) v = KEY_MAX_IDENT;
    else {
        int off = (i - 2) % 13;
        bool ismin = (off==3 || off==7 || off==8 || off==9);
        bool ismax = (off==0 || off==11 || off==12);
        v = ismin ? KEY_MIN_IDENT : (ismax ? KEY_MAX_IDENT : 0u);
    }
    R[i] = v;
}

// -------- state0: F0=err(y0), jac0 (as sj), rn0, fobj0 --------
__global__ __launch_bounds__(256) void kInit(
    const float* __restrict__ y0g, const float* __restrict__ Wm, const float* __restrict__ Vm,
    const float* __restrict__ dtp, const float* __restrict__ tp, float* __restrict__ ws)
{
    __shared__ float sW[64], sV[64];
    __shared__ float bred[2][4];
    int t = threadIdx.x;
    if (t < 64) sW[t] = Wm[t];
    else if (t < 128) sV[t-64] = Vm[t-64];
    __syncthreads();
    unsigned* R = (unsigned*)(ws + OFF_R);
    int tid = blockIdx.x*256 + t;
    bool valid = tid < BSZ;
    float c0 = 0.01f * sinf(*tp);
    float rn = -__builtin_inff(), ratio = -__builtin_inff();
    if (valid){
        float y[8]; ld8(y0g + (size_t)tid*8, y);
        float u[8], z[8], sj[8];
        #pragma unroll
        for (int k=0;k<8;k++){
            float acc = 0.f;
            #pragma unroll
            for (int m=0;m<8;m++) acc += y[m]*sW[m*8+k];
            u[k]=acc;
        }
        #pragma unroll
        for (int k=0;k<8;k++){ z[k]=tanhf(u[k]); sj[k]=1.0f - z[k]*z[k]; }
        float Fn[8];
        #pragma unroll
        for (int i=0;i<8;i++){
            float tv = 0.f;
            #pragma unroll
            for (int k=0;k<8;k++) tv += z[k]*sV[k*8+i];
            Fn[i] = 0.0f - ((tv - 0.1f*y[i]) + c0);   // (y0-y0)/dt == 0
        }
        float fold = 0.f;
        #pragma unroll
        for (int i=0;i<8;i++) fold += Fn[i]*Fn[i];
        float rn0 = fabsf(Fn[0]);
        #pragma unroll
        for (int i=1;i<8;i++) rn0 = nanmax2(rn0, fabsf(Fn[i]));
        float zero8[8] = {0,0,0,0,0,0,0,0};
        st8(ws+OFF_Y   +(size_t)tid*8, y);
        st8(ws+OFF_YOLD+(size_t)tid*8, y);
        st8(ws+OFF_F   +(size_t)tid*8, Fn);
        st8(ws+OFF_DY  +(size_t)tid*8, zero8);
        st8(ws+OFF_SJ  +(size_t)tid*8, sj);
        ws[OFF_FOLD+tid]=fold; ws[OFF_SLOPE+tid]=0.0f;
        ws[OFF_RESN+tid]=rn0;  ws[OFF_F2+tid]=fold;
        ws[OFF_TRN+tid]=0.0f;  ws[OFF_TFO+tid]=0.0f;
        rn = rn0;
        ratio = safe_div(rn0, 100.0f*rn0);   // resnorm0 = 100*rn0
    }
    #pragma unroll
    for (int o=32;o>=1;o>>=1){
        rn    = nanmax2(rn,    __shfl_xor(rn,    o, 64));
        ratio = nanmax2(ratio, __shfl_xor(ratio, o, 64));
    }
    int w = t >> 6;
    if ((t & 63) == 0){ bred[0][w] = rn; bred[1][w] = ratio; }
    __syncthreads();
    if (t == 0){
        float a = nanmax2(nanmax2(bred[0][0],bred[0][1]), nanmax2(bred[0][2],bred[0][3]));
        float b = nanmax2(nanmax2(bred[1][0],bred[1][1]), nanmax2(bred[1][2],bred[1][3]));
        atomicMax(&R[0], fkey_max(a));
        atomicMax(&R[1], fkey_max(b));
    }
}

// -------- phase A: Newton direction (jac select, solve, slope, fold, lam_min input) --------
__global__ __launch_bounds__(256) void phaseA(
    const float* __restrict__ Wm, const float* __restrict__ Vm,
    const float* __restrict__ dtp, float* __restrict__ ws, int step)
{
    __shared__ float sW[64], sV[64];
    __shared__ float ared[4];
    __shared__ unsigned abred[4];
    int t = threadIdx.x;
    if (t < 64) sW[t] = Wm[t];
    else if (t < 128) sV[t-64] = Vm[t-64];
    __syncthreads();

    unsigned* R = (unsigned*)(ws + OFF_R);
    ScalarState S = replay(R, step-1);
    bool active    = ((S.maxrn > TOLFUN_C) || (S.lam < 1.0f)) && (S.exitflag >= 0) && (S.niter <= 1000);
    bool is_newton = (S.lam == 1.0f);
    if (!active || !is_newton) return;   // uniform
    bool recompute = (S.ratmax > 0.2f);

    int tid = blockIdx.x*256 + t;
    bool valid = tid < BSZ;
    float invdt = 1.0f / (*dtp);
    float gml = -__builtin_inff();
    bool nf = false;

    if (valid){
        float y[8], Fv[8], sj[8];
        ld8(ws+OFF_Y+(size_t)tid*8, y);
        ld8(ws+OFF_F+(size_t)tid*8, Fv);
        if (recompute){
            float u[8];
            #pragma unroll
            for (int k=0;k<8;k++){
                float acc = 0.f;
                #pragma unroll
                for (int m=0;m<8;m++) acc += y[m]*sW[m*8+k];
                u[k]=acc;
            }
            #pragma unroll
            for (int k=0;k<8;k++){ float z = tanhf(u[k]); sj[k] = 1.0f - z*z; }
            st8(ws+OFF_SJ+(size_t)tid*8, sj);   // eager commit (safe: upd-false => frozen forever)
        } else {
            ld8(ws+OFF_SJ+(size_t)tid*8, sj);
        }
        // J[i][j] = d err_i / d y_j = delta/dt - ( sum_k (W[j,k]*s_k) V[k,i] - 0.1*delta )
        float J[8][8];
        #pragma unroll
        for (int j=0;j<8;j++){
            float zj[8];
            #pragma unroll
            for (int k=0;k<8;k++) zj[k] = sW[j*8+k]*sj[k];
            #pragma unroll
            for (int i=0;i<8;i++){
                float acc = 0.f;
                #pragma unroll
                for (int k=0;k<8;k++) acc += zj[k]*sV[k*8+i];
                J[i][j] = (i==j) ? (invdt - (acc - 0.1f)) : (0.0f - acc);
            }
        }
        float fold = 0.f;
        #pragma unroll
        for (int i=0;i<8;i++) fold += Fv[i]*Fv[i];
        float gv[8];
        #pragma unroll
        for (int j=0;j<8;j++){
            float acc = 0.f;
            #pragma unroll
            for (int i=0;i<8;i++) acc += Fv[i]*J[i][j];
            gv[j]=acc;
        }
        // solve J x = F (no-pivot GE; J strongly diagonally dominant)
        float x[8];
        #pragma unroll
        for (int i=0;i<8;i++) x[i]=Fv[i];
        #pragma unroll
        for (int c=0;c<8;c++){
            float ip = 1.0f / J[c][c];
            #pragma unroll
            for (int r2=c+1;r2<8;r2++){
                float m = J[r2][c]*ip;
                #pragma unroll
                for (int jj=c+1;jj<8;jj++) J[r2][jj] -= m*J[c][jj];
                x[r2] -= m*x[c];
            }
        }
        float wv[8];
        #pragma unroll
        for (int c=7;c>=0;c--){
            float acc = x[c];
            #pragma unroll
            for (int jj=c+1;jj<8;jj++) acc -= J[c][jj]*wv[jj];
            wv[c] = acc / J[c][c];
        }
        float dy[8];
        #pragma unroll
        for (int i=0;i<8;i++) dy[i] = -wv[i];
        float slope = 0.f;
        #pragma unroll
        for (int j=0;j<8;j++) slope += gv[j]*dy[j];
        st8(ws+OFF_DY  +(size_t)tid*8, dy);
        st8(ws+OFF_YOLD+(size_t)tid*8, y);
        ws[OFF_FOLD+tid]  = fold;
        ws[OFF_SLOPE+tid] = slope;
        #pragma unroll
        for (int i=0;i<8;i++){
            float rr = fabsf(dy[i]) / nanmax2(fabsf(y[i]), 1.0f);
            gml = nanmax2(gml, rr);
            nf = nf || !__builtin_isfinite(dy[i]);
        }
    }
    #pragma unroll
    for (int o=32;o>=1;o>>=1) gml = nanmax2(gml, __shfl_xor(gml, o, 64));
    unsigned long long anym = __ballot(nf ? 1 : 0);
    int w = t >> 6;
    if ((t & 63) == 0){ ared[w] = gml; abred[w] = anym ? 1u : 0u; }
    __syncthreads();
    if (t == 0){
        unsigned* r1 = R + 2 + (step-1)*13;
        float v = nanmax2(nanmax2(ared[0],ared[1]), nanmax2(ared[2],ared[3]));
        atomicMax(&r1[0], fkey_max(v));
        unsigned bm = abred[0]|abred[1]|abred[2]|abred[3];
        if (bm) atomicOr(&r1[1], 1u);
    }
}

// -------- phase B: trial step + line-search reductions + commits --------
__global__ __launch_bounds__(256) void phaseB(
    const float* __restrict__ y0g, const float* __restrict__ Wm, const float* __restrict__ Vm,
    const float* __restrict__ dtp, const float* __restrict__ tp,
    float* __restrict__ ws, int step)
{
    __shared__ float sW[64], sV[64];
    __shared__ float fred[6][4];
    __shared__ unsigned bbred[4];
    int t = threadIdx.x;
    if (t < 64) sW[t] = Wm[t];
    else if (t < 128) sV[t-64] = Vm[t-64];
    __syncthreads();

    unsigned* R = (unsigned*)(ws + OFF_R);
    ScalarState S = replay(R, step-1);
    bool active    = ((S.maxrn > TOLFUN_C) || (S.lam < 1.0f)) && (S.exitflag >= 0) && (S.niter <= 1000);
    bool is_newton = (S.lam == 1.0f);
    unsigned* r = R + 2 + (step-1)*13;
    float lam_min_new = is_newton ? safe_div(1e-12f, funkey(r[0])) : S.lam_min;
    bool brk = (S.lam < lam_min_new);
    bool bad = is_newton ? (r[1] != 0u) : false;
    bool upd = active && !brk && !bad;
    if (!upd) return;   // uniform; upd-false is permanent

    int tid = blockIdx.x*256 + t;
    bool valid = tid < BSZ;
    float dt = *dtp;
    float c0 = 0.01f * sinf(*tp);
    float lam = S.lam, lam2 = S.lam2;

    bool armijo=false, aNot0=false, dN=false, ble=false, nanf=false;
    float lq = __builtin_inff(), mX = __builtin_inff(), mZ = __builtin_inff(), mW = __builtin_inff();
    float trn = -__builtin_inff(), ratio = -__builtin_inff();

    if (valid){
        // lazy commits from previous step (f2 / resnorm depend on prev cont)
        float f2v   = ws[OFF_F2+tid];
        float rnold = ws[OFF_RESN+tid];
        if (S.upd_prev){
            if (S.cont_prev){ f2v = ws[OFF_TFO+tid]; ws[OFF_F2+tid] = f2v; }
            else            { rnold = ws[OFF_TRN+tid]; ws[OFF_RESN+tid] = rnold; }
        }
        float foldv  = ws[OFF_FOLD+tid];
        float slopev = ws[OFF_SLOPE+tid];
        float yold[8], dyv[8];
        ld8(ws+OFF_YOLD+(size_t)tid*8, yold);
        ld8(ws+OFF_DY  +(size_t)tid*8, dyv);
        float yn[8];
        #pragma unroll
        for (int i=0;i<8;i++) yn[i] = yold[i] + dyv[i]*lam;
        float u[8], z[8];
        #pragma unroll
        for (int k=0;k<8;k++){
            float acc = 0.f;
            #pragma unroll
            for (int m=0;m<8;m++) acc += yn[m]*sW[m*8+k];
            u[k]=acc;
        }
        #pragma unroll
        for (int k=0;k<8;k++) z[k] = tanhf(u[k]);
        float Fn[8];
        #pragma unroll
        for (int i=0;i<8;i++){
            float tv = 0.f;
            #pragma unroll
            for (int k=0;k<8;k++) tv += z[k]*sV[k*8+i];
            Fn[i] = (yn[i] - y0g[(size_t)tid*8+i])/dt - ((tv - 0.1f*yn[i]) + c0);
        }
        float f_obj = 0.f;
        #pragma unroll
        for (int i=0;i<8;i++) f_obj += Fn[i]*Fn[i];
        st8(ws+OFF_Y+(size_t)tid*8, yn);
        st8(ws+OFF_F+(size_t)tid*8, Fn);
        float rn = fabsf(Fn[0]);
        #pragma unroll
        for (int i=1;i<8;i++) rn = nanmax2(rn, fabsf(Fn[i]));
        ws[OFF_TRN+tid] = rn;
        ws[OFF_TFO+tid] = f_obj;

        armijo = f_obj > (foldv + (ALPHA_C*lam)*slopev);
        lq = safe_div((-slopev)*0.5f, (f_obj - foldv) - slopev);
        float lam1v = lam;
        float Af = safe_div(1.0f, lam1v - lam2);
        float i1 = safe_div(1.0f, lam1v*lam1v);
        float i2 = safe_div(1.0f, lam2*lam2);
        float Cc0 = (f_obj - foldv) - lam1v*slopev;
        float Cc1 = (f2v  - foldv) - lam2 *slopev;
        float av = Af*(i1*Cc0 - i2*Cc1);
        float bv = Af*((-(lam2*i1))*Cc0 + (lam1v*i2)*Cc1);
        float disc = bv*bv - (3.0f*av)*slopev;
        float dm = __builtin_isnan(disc) ? disc : fmaxf(disc, 0.0f);  // jnp.maximum NaN-prop
        float sq = sqrtf(dm);
        aNot0 = (av != 0.0f);
        dN    = (disc < 0.0f);
        ble   = (bv <= 0.0f);
        mX = safe_div(-slopev, 2.0f*bv);
        mZ = safe_div(-bv + sq, 3.0f*av);
        mW = safe_div(-slopev, bv + sq);
        nanf = !__builtin_isfinite(f_obj);
        trn = rn;
        ratio = safe_div(rn, rnold);
    }
    #pragma unroll
    for (int o=32;o>=1;o>>=1){
        lq    = nanmin2(lq,    __shfl_xor(lq,    o, 64));
        mX    = nanmin2(mX,    __shfl_xor(mX,    o, 64));
        mZ    = nanmin2(mZ,    __shfl_xor(mZ,    o, 64));
        mW    = nanmin2(mW,    __shfl_xor(mW,    o, 64));
        trn   = nanmax2(trn,   __shfl_xor(trn,   o, 64));
        ratio = nanmax2(ratio, __shfl_xor(ratio, o, 64));
    }
    unsigned long long bArm = __ballot(armijo ? 1 : 0);
    unsigned long long bA0  = __ballot(aNot0  ? 1 : 0);
    unsigned long long bDN  = __ballot(dN     ? 1 : 0);
    unsigned long long bB0  = __ballot(ble    ? 1 : 0);
    unsigned long long bNF  = __ballot(nanf   ? 1 : 0);
    int w = t >> 6;
    if ((t & 63) == 0){
        fred[0][w]=lq; fred[1][w]=mX; fred[2][w]=mZ; fred[3][w]=mW;
        fred[4][w]=trn; fred[5][w]=ratio;
        bbred[w] = (bArm?1u:0u) | (bA0?2u:0u) | (bDN?4u:0u) | (bB0?8u:0u) | (bNF?16u:0u);
    }
    __syncthreads();
    // one atomic per block per slot (13 addresses, 782 blocks) instead of per wave
    if (t < 6){
        float v = fred[t][0];
        bool ismin = (t < 4);
        #pragma unroll
        for (int w2=1; w2<4; ++w2) v = ismin ? nanmin2(v, fred[t][w2]) : nanmax2(v, fred[t][w2]);
        const int slot_idx[6] = {3,7,8,9,11,12};
        if (ismin) atomicMin(&r[slot_idx[t]], fkey_min(v));
        else       atomicMax(&r[slot_idx[t]], fkey_max(v));
    } else if (t == 6){
        unsigned bm = bbred[0]|bbred[1]|bbred[2]|bbred[3];
        if (bm & 1u)  atomicOr(&r[2], 1u);
        if (bm & 2u)  atomicOr(&r[4], 1u);
        if (bm & 4u)  atomicOr(&r[5], 1u);
        if (bm & 8u)  atomicOr(&r[6], 1u);
        if (bm & 16u) atomicOr(&r[10], 1u);
    }
}

// -------- output: y, F, exitflag --------
__global__ __launch_bounds__(256) void kOut(const float* __restrict__ ws, float* __restrict__ out)
{
    const unsigned* R = (const unsigned*)(ws + OFF_R);
    ScalarState S = replay(R, NSTEPS);
    int tid = blockIdx.x*256 + threadIdx.x;
    if (tid < BSZ){
        float v[8];
        ld8(ws+OFF_Y+(size_t)tid*8, v);
        st8(out + (size_t)tid*8, v);
        ld8(ws+OFF_F+(size_t)tid*8, v);
        st8(out + (size_t)BSZ*8 + (size_t)tid*8, v);
    }
    if (tid == 0) out[(size_t)BSZ*16] = (float)S.exitflag;
}

extern "C" void kernel_launch(void* const* d_in, const int* in_sizes, int n_in,
                              void* d_out, int out_size, void* d_ws, size_t ws_size,
                              hipStream_t stream)
{
    const float* y0g = (const float*)d_in[0];
    const float* dtp = (const float*)d_in[1];
    const float* tp  = (const float*)d_in[2];
    const float* Wm  = (const float*)d_in[3];
    const float* Vm  = (const float*)d_in[4];
    float* ws  = (float*)d_ws;
    float* out = (float*)d_out;
    dim3 grid((BSZ + 255)/256), blk(256);

    hipLaunchKernelGGL(kPre, dim3(1), dim3(256), 0, stream, (unsigned*)(ws + OFF_R));
    hipLaunchKernelGGL(kInit, grid, blk, 0, stream, y0g, Wm, Vm, dtp, tp, ws);
    for (int s = 1; s <= NSTEPS; ++s){
        hipLaunchKernelGGL(phaseA, grid, blk, 0, stream, Wm, Vm, dtp, ws, s);
        hipLaunchKernelGGL(phaseB, grid, blk, 0, stream, y0g, Wm, Vm, dtp, tp, ws, s);
    }
    hipLaunchKernelGGL(kOut, grid, blk, 0, stream, ws, out);
}

// Round 3
// 459.391 us; speedup vs baseline: 6.9883x; 1.6825x over previous
//
#include <hip/hip_runtime.h>

#define BSZ 200000
#define NSTEPS 10
#define TOLFUN_C 1e-6f
#define ALPHA_C 1e-4f

// ---------------- ws layout (float elements) ----------------
#define OFF_Y     ((size_t)0)
#define OFF_YOLD  ((size_t)BSZ*8)
#define OFF_F     ((size_t)BSZ*16)
#define OFF_DY    ((size_t)BSZ*24)
#define OFF_SJ    ((size_t)BSZ*32)
#define OFF_FOLD  ((size_t)BSZ*40)
#define OFF_SLOPE ((size_t)BSZ*41)
#define OFF_RESN  ((size_t)BSZ*42)
#define OFF_F2    ((size_t)BSZ*43)
#define OFF_TRN   ((size_t)BSZ*44)
#define OFF_TFO   ((size_t)BSZ*45)
#define OFF_R     ((size_t)BSZ*46)

// Reduction slots, each padded to its own 256B cache-line region so atomics
// to different slots don't serialize on one TCC line.
#define RSTRIDE 64            /* uint words = 256 B */
#define NSLOT   9
#define R_TOT   (2 + NSTEPS*NSLOT)
// global: slot0 = max(rn0) key, slot1 = max(ratio0) key
// per step j, base 2+j*9:
//  +0 maxGml(maxkey) +1 anyNFdy(bit) +2 minQuad(minkey) +3 minX(minkey)
//  +4 minZ(minkey) +5 minW(minkey) +6 maxTRN(maxkey) +7 maxRatio(maxkey)
//  +8 boolmask: bit0 anyArmijo, bit1 anyAnot0, bit2 anyDiscNeg, bit3 anyBle0, bit4 anyNanF
#define KEY_MAX_IDENT 0x007FFFFFu  /* fkey(-inf) */
#define KEY_MIN_IDENT 0xFF800000u  /* fkey(+inf) */

static __device__ __forceinline__ float nanmax2(float a, float b){
    return (__builtin_isnan(a) || __builtin_isnan(b)) ? __builtin_nanf("") : fmaxf(a, b);
}
static __device__ __forceinline__ float nanmin2(float a, float b){
    return (__builtin_isnan(a) || __builtin_isnan(b)) ? __builtin_nanf("") : fminf(a, b);
}
static __device__ __forceinline__ float safe_div(float n, float d){
    return (fabsf(d) > 1e-30f) ? (n / d) : 0.0f;   // matches jnp _safe_div incl. NaN denom -> 0
}
// monotone float->uint key (works with atomicMax/Min on unsigned)
static __device__ __forceinline__ unsigned fkey(float x){
    unsigned u = __float_as_uint(x);
    return (u & 0x80000000u) ? ~u : (u | 0x80000000u);
}
static __device__ __forceinline__ float funkey(unsigned u){
    return (u & 0x80000000u) ? __uint_as_float(u & 0x7FFFFFFFu) : __uint_as_float(~u);
}
static __device__ __forceinline__ unsigned fkey_max(float x){
    if (__builtin_isnan(x)) x = __uint_as_float(0x7FC00000u); // +NaN: dominates max
    return fkey(x);
}
static __device__ __forceinline__ unsigned fkey_min(float x){
    if (__builtin_isnan(x)) x = __uint_as_float(0xFFC00000u); // -NaN: dominates min
    return fkey(x);
}
static __device__ __forceinline__ void ld8(const float* p, float* v){
    float4 a = ((const float4*)p)[0], b = ((const float4*)p)[1];
    v[0]=a.x; v[1]=a.y; v[2]=a.z; v[3]=a.w; v[4]=b.x; v[5]=b.y; v[6]=b.z; v[7]=b.w;
}
static __device__ __forceinline__ void st8(float* p, const float* v){
    float4 a, b;
    a.x=v[0]; a.y=v[1]; a.z=v[2]; a.w=v[3];
    b.x=v[4]; b.y=v[5]; b.z=v[6]; b.w=v[7];
    ((float4*)p)[0]=a; ((float4*)p)[1]=b;
}

struct ScalarState {
    float lam, lam1, lam2, lam_min, maxrn, ratmax;
    int   niter, exitflag;
    bool  upd_prev, cont_prev;
};

// Deterministically replay the global scalar control chain from the stored
// per-step reduction slots. Every thread does this redundantly.
static __device__ ScalarState replay(const unsigned* R, int nsteps_done){
    ScalarState s;
    s.lam = 1.0f; s.lam1 = 1.0f; s.lam2 = 0.5f; s.lam_min = 0.0f;
    s.maxrn  = funkey(R[0]);
    s.ratmax = funkey(R[(size_t)1*RSTRIDE]);
    s.niter = 0; s.exitflag = 1;
    s.upd_prev = false; s.cont_prev = false;
    for (int j = 0; j < nsteps_done; ++j){
        const unsigned* r = R + (size_t)(2 + j*NSLOT)*RSTRIDE;
        bool active    = ((s.maxrn > TOLFUN_C) || (s.lam < 1.0f)) && (s.exitflag >= 0) && (s.niter <= 1000);
        bool is_newton = (s.lam == 1.0f);
        float lam_min_new = is_newton ? safe_div(1e-12f, funkey(r[0])) : s.lam_min;
        bool brk = (s.lam < lam_min_new);
        bool bad = is_newton ? (r[(size_t)1*RSTRIDE] != 0u) : false;
        bool upd = active && !brk && !bad;
        int niter_new = active ? (is_newton ? s.niter + 1 : s.niter) : s.niter;
        int ef_new = s.exitflag;
        if (active && brk) ef_new = 2;
        else if (active && !brk && bad) ef_new = -1;
        bool cont = false;
        if (upd){
            float lam1c = s.lam;
            unsigned bm = r[(size_t)8*RSTRIDE];
            bool backtrack = (bm & 1u) != 0u;
            float lamq  = funkey(r[(size_t)2*RSTRIDE]);
            bool allA0  = (bm & 2u) == 0u;
            bool anyDN  = (bm & 4u) != 0u;
            bool anyB0  = (bm & 8u) != 0u;
            float lam_tmp_min = allA0 ? funkey(r[(size_t)3*RSTRIDE])
                              : (anyDN ? (0.5f*lam1c)
                              : (anyB0 ? funkey(r[(size_t)4*RSTRIDE]) : funkey(r[(size_t)5*RSTRIDE])));
            float lam_cubic = nanmin2(lam_tmp_min, 0.5f*lam1c);
            float lam_bt = (s.lam == 1.0f) ? lamq : lam_cubic;
            bool nanf = (bm & 16u) != 0u;
            float lam_new = backtrack ? lam_bt : (nanf ? 0.5f*lam1c : 1.0f);
            cont = (lam_new < 1.0f);
            float lam2_new = cont ? lam1c : s.lam2;
            if (cont) lam_new = nanmax2(lam_new, 0.1f*lam1c);
            float maxrn_new  = cont ? s.maxrn  : funkey(r[(size_t)6*RSTRIDE]);
            float ratmax_new = cont ? s.ratmax : funkey(r[(size_t)7*RSTRIDE]);
            s.lam = lam_new; s.lam1 = lam1c; s.lam2 = lam2_new;
            s.lam_min = lam_min_new; s.maxrn = maxrn_new; s.ratmax = ratmax_new;
        }
        s.niter = niter_new; s.exitflag = ef_new;
        s.upd_prev = upd; s.cont_prev = cont;
    }
    return s;
}

// -------- init reduction slots to identities (d_ws is poisoned 0xAA) --------
__global__ void kPre(unsigned* __restrict__ R){
    int i = threadIdx.x;
    if (i >= R_TOT) return;
    unsigned v;
    if (i < 2) v = KEY_MAX_IDENT;
    else {
        int off = (i - 2) % NSLOT;
        bool ismin = (off==2 || off==3 || off==4 || off==5);
        bool ismax = (off==0 || off==6 || off==7);
        v = ismin ? KEY_MIN_IDENT : (ismax ? KEY_MAX_IDENT : 0u);
    }
    R[(size_t)i*RSTRIDE] = v;
}

// -------- state0: F0=err(y0), jac0 (as sj), rn0, fobj0 --------
__global__ __launch_bounds__(256) void kInit(
    const float* __restrict__ y0g, const float* __restrict__ Wm, const float* __restrict__ Vm,
    const float* __restrict__ dtp, const float* __restrict__ tp, float* __restrict__ ws)
{
    __shared__ float sW[64], sV[64];
    __shared__ float bred[2][4];
    int t = threadIdx.x;
    if (t < 64) sW[t] = Wm[t];
    else if (t < 128) sV[t-64] = Vm[t-64];
    __syncthreads();
    unsigned* R = (unsigned*)(ws + OFF_R);
    int tid = blockIdx.x*256 + t;
    bool valid = tid < BSZ;
    float c0 = 0.01f * sinf(*tp);
    float rn = -__builtin_inff(), ratio = -__builtin_inff();
    if (valid){
        float y[8]; ld8(y0g + (size_t)tid*8, y);
        float u[8], z[8], sj[8];
        #pragma unroll
        for (int k=0;k<8;k++){
            float acc = 0.f;
            #pragma unroll
            for (int m=0;m<8;m++) acc += y[m]*sW[m*8+k];
            u[k]=acc;
        }
        #pragma unroll
        for (int k=0;k<8;k++){ z[k]=tanhf(u[k]); sj[k]=1.0f - z[k]*z[k]; }
        float Fn[8];
        #pragma unroll
        for (int i=0;i<8;i++){
            float tv = 0.f;
            #pragma unroll
            for (int k=0;k<8;k++) tv += z[k]*sV[k*8+i];
            Fn[i] = 0.0f - ((tv - 0.1f*y[i]) + c0);   // (y0-y0)/dt == 0
        }
        float fold = 0.f;
        #pragma unroll
        for (int i=0;i<8;i++) fold += Fn[i]*Fn[i];
        float rn0 = fabsf(Fn[0]);
        #pragma unroll
        for (int i=1;i<8;i++) rn0 = nanmax2(rn0, fabsf(Fn[i]));
        float zero8[8] = {0,0,0,0,0,0,0,0};
        st8(ws+OFF_Y   +(size_t)tid*8, y);
        st8(ws+OFF_YOLD+(size_t)tid*8, y);
        st8(ws+OFF_F   +(size_t)tid*8, Fn);
        st8(ws+OFF_DY  +(size_t)tid*8, zero8);
        st8(ws+OFF_SJ  +(size_t)tid*8, sj);
        ws[OFF_FOLD+tid]=fold; ws[OFF_SLOPE+tid]=0.0f;
        ws[OFF_RESN+tid]=rn0;  ws[OFF_F2+tid]=fold;
        ws[OFF_TRN+tid]=0.0f;  ws[OFF_TFO+tid]=0.0f;
        rn = rn0;
        ratio = safe_div(rn0, 100.0f*rn0);   // resnorm0 = 100*rn0
    }
    #pragma unroll
    for (int o=32;o>=1;o>>=1){
        rn    = nanmax2(rn,    __shfl_xor(rn,    o, 64));
        ratio = nanmax2(ratio, __shfl_xor(ratio, o, 64));
    }
    int w = t >> 6;
    if ((t & 63) == 0){ bred[0][w] = rn; bred[1][w] = ratio; }
    __syncthreads();
    if (t == 0){
        float a = nanmax2(nanmax2(bred[0][0],bred[0][1]), nanmax2(bred[0][2],bred[0][3]));
        atomicMax(&R[0], fkey_max(a));
    } else if (t == 1){
        float b = nanmax2(nanmax2(bred[1][0],bred[1][1]), nanmax2(bred[1][2],bred[1][3]));
        atomicMax(&R[(size_t)1*RSTRIDE], fkey_max(b));
    }
}

// -------- phase A: Newton direction (jac select, solve, slope, fold, lam_min input) --------
__global__ __launch_bounds__(256) void phaseA(
    const float* __restrict__ Wm, const float* __restrict__ Vm,
    const float* __restrict__ dtp, float* __restrict__ ws, int step)
{
    __shared__ float sW[64], sV[64];
    __shared__ float ared[4];
    __shared__ unsigned abred[4];
    int t = threadIdx.x;
    if (t < 64) sW[t] = Wm[t];
    else if (t < 128) sV[t-64] = Vm[t-64];
    __syncthreads();

    unsigned* R = (unsigned*)(ws + OFF_R);
    ScalarState S = replay(R, step-1);
    bool active    = ((S.maxrn > TOLFUN_C) || (S.lam < 1.0f)) && (S.exitflag >= 0) && (S.niter <= 1000);
    bool is_newton = (S.lam == 1.0f);
    if (!active || !is_newton) return;   // uniform
    bool recompute = (S.ratmax > 0.2f);

    int tid = blockIdx.x*256 + t;
    bool valid = tid < BSZ;
    float invdt = 1.0f / (*dtp);
    float gml = -__builtin_inff();
    bool nf = false;

    if (valid){
        float y[8], Fv[8], sj[8];
        ld8(ws+OFF_Y+(size_t)tid*8, y);
        ld8(ws+OFF_F+(size_t)tid*8, Fv);
        if (recompute){
            float u[8];
            #pragma unroll
            for (int k=0;k<8;k++){
                float acc = 0.f;
                #pragma unroll
                for (int m=0;m<8;m++) acc += y[m]*sW[m*8+k];
                u[k]=acc;
            }
            #pragma unroll
            for (int k=0;k<8;k++){ float z = tanhf(u[k]); sj[k] = 1.0f - z*z; }
            st8(ws+OFF_SJ+(size_t)tid*8, sj);   // eager commit (safe: upd-false => frozen forever)
        } else {
            ld8(ws+OFF_SJ+(size_t)tid*8, sj);
        }
        // J[i][j] = d err_i / d y_j = delta/dt - ( sum_k (W[j,k]*s_k) V[k,i] - 0.1*delta )
        float J[8][8];
        #pragma unroll
        for (int j=0;j<8;j++){
            float zj[8];
            #pragma unroll
            for (int k=0;k<8;k++) zj[k] = sW[j*8+k]*sj[k];
            #pragma unroll
            for (int i=0;i<8;i++){
                float acc = 0.f;
                #pragma unroll
                for (int k=0;k<8;k++) acc += zj[k]*sV[k*8+i];
                J[i][j] = (i==j) ? (invdt - (acc - 0.1f)) : (0.0f - acc);
            }
        }
        float fold = 0.f;
        #pragma unroll
        for (int i=0;i<8;i++) fold += Fv[i]*Fv[i];
        float gv[8];
        #pragma unroll
        for (int j=0;j<8;j++){
            float acc = 0.f;
            #pragma unroll
            for (int i=0;i<8;i++) acc += Fv[i]*J[i][j];
            gv[j]=acc;
        }
        // solve J x = F (no-pivot GE; J strongly diagonally dominant)
        float x[8];
        #pragma unroll
        for (int i=0;i<8;i++) x[i]=Fv[i];
        #pragma unroll
        for (int c=0;c<8;c++){
            float ip = 1.0f / J[c][c];
            #pragma unroll
            for (int r2=c+1;r2<8;r2++){
                float m = J[r2][c]*ip;
                #pragma unroll
                for (int jj=c+1;jj<8;jj++) J[r2][jj] -= m*J[c][jj];
                x[r2] -= m*x[c];
            }
        }
        float wv[8];
        #pragma unroll
        for (int c=7;c>=0;c--){
            float acc = x[c];
            #pragma unroll
            for (int jj=c+1;jj<8;jj++) acc -= J[c][jj]*wv[jj];
            wv[c] = acc / J[c][c];
        }
        float dy[8];
        #pragma unroll
        for (int i=0;i<8;i++) dy[i] = -wv[i];
        float slope = 0.f;
        #pragma unroll
        for (int j=0;j<8;j++) slope += gv[j]*dy[j];
        st8(ws+OFF_DY  +(size_t)tid*8, dy);
        st8(ws+OFF_YOLD+(size_t)tid*8, y);
        ws[OFF_FOLD+tid]  = fold;
        ws[OFF_SLOPE+tid] = slope;
        #pragma unroll
        for (int i=0;i<8;i++){
            float rr = fabsf(dy[i]) / nanmax2(fabsf(y[i]), 1.0f);
            gml = nanmax2(gml, rr);
            nf = nf || !__builtin_isfinite(dy[i]);
        }
    }
    #pragma unroll
    for (int o=32;o>=1;o>>=1) gml = nanmax2(gml, __shfl_xor(gml, o, 64));
    unsigned long long anym = __ballot(nf ? 1 : 0);
    int w = t >> 6;
    if ((t & 63) == 0){ ared[w] = gml; abred[w] = anym ? 1u : 0u; }
    __syncthreads();
    unsigned* r1 = R + (size_t)(2 + (step-1)*NSLOT)*RSTRIDE;
    if (t == 0){
        float v = nanmax2(nanmax2(ared[0],ared[1]), nanmax2(ared[2],ared[3]));
        atomicMax(&r1[0], fkey_max(v));
    } else if (t == 1){
        unsigned bm = abred[0]|abred[1]|abred[2]|abred[3];
        if (bm) atomicOr(&r1[(size_t)1*RSTRIDE], 1u);
    }
}

// -------- phase B: trial step + line-search reductions + commits --------
__global__ __launch_bounds__(256) void phaseB(
    const float* __restrict__ y0g, const float* __restrict__ Wm, const float* __restrict__ Vm,
    const float* __restrict__ dtp, const float* __restrict__ tp,
    float* __restrict__ ws, int step)
{
    __shared__ float sW[64], sV[64];
    __shared__ float fred[6][4];
    __shared__ unsigned bbred[4];
    int t = threadIdx.x;
    if (t < 64) sW[t] = Wm[t];
    else if (t < 128) sV[t-64] = Vm[t-64];
    __syncthreads();

    unsigned* R = (unsigned*)(ws + OFF_R);
    ScalarState S = replay(R, step-1);
    bool active    = ((S.maxrn > TOLFUN_C) || (S.lam < 1.0f)) && (S.exitflag >= 0) && (S.niter <= 1000);
    bool is_newton = (S.lam == 1.0f);
    unsigned* r = R + (size_t)(2 + (step-1)*NSLOT)*RSTRIDE;
    float lam_min_new = is_newton ? safe_div(1e-12f, funkey(r[0])) : S.lam_min;
    bool brk = (S.lam < lam_min_new);
    bool bad = is_newton ? (r[(size_t)1*RSTRIDE] != 0u) : false;
    bool upd = active && !brk && !bad;
    if (!upd) return;   // uniform; upd-false is permanent

    int tid = blockIdx.x*256 + t;
    bool valid = tid < BSZ;
    float dt = *dtp;
    float c0 = 0.01f * sinf(*tp);
    float lam = S.lam, lam2 = S.lam2;

    bool armijo=false, aNot0=false, dN=false, ble=false, nanf=false;
    float lq = __builtin_inff(), mX = __builtin_inff(), mZ = __builtin_inff(), mW = __builtin_inff();
    float trn = -__builtin_inff(), ratio = -__builtin_inff();

    if (valid){
        // lazy commits from previous step (f2 / resnorm depend on prev cont)
        float f2v   = ws[OFF_F2+tid];
        float rnold = ws[OFF_RESN+tid];
        if (S.upd_prev){
            if (S.cont_prev){ f2v = ws[OFF_TFO+tid]; ws[OFF_F2+tid] = f2v; }
            else            { rnold = ws[OFF_TRN+tid]; ws[OFF_RESN+tid] = rnold; }
        }
        float foldv  = ws[OFF_FOLD+tid];
        float slopev = ws[OFF_SLOPE+tid];
        float yold[8], dyv[8];
        ld8(ws+OFF_YOLD+(size_t)tid*8, yold);
        ld8(ws+OFF_DY  +(size_t)tid*8, dyv);
        float yn[8];
        #pragma unroll
        for (int i=0;i<8;i++) yn[i] = yold[i] + dyv[i]*lam;
        float u[8], z[8];
        #pragma unroll
        for (int k=0;k<8;k++){
            float acc = 0.f;
            #pragma unroll
            for (int m=0;m<8;m++) acc += yn[m]*sW[m*8+k];
            u[k]=acc;
        }
        #pragma unroll
        for (int k=0;k<8;k++) z[k] = tanhf(u[k]);
        float Fn[8];
        #pragma unroll
        for (int i=0;i<8;i++){
            float tv = 0.f;
            #pragma unroll
            for (int k=0;k<8;k++) tv += z[k]*sV[k*8+i];
            Fn[i] = (yn[i] - y0g[(size_t)tid*8+i])/dt - ((tv - 0.1f*yn[i]) + c0);
        }
        float f_obj = 0.f;
        #pragma unroll
        for (int i=0;i<8;i++) f_obj += Fn[i]*Fn[i];
        st8(ws+OFF_Y+(size_t)tid*8, yn);
        st8(ws+OFF_F+(size_t)tid*8, Fn);
        float rn = fabsf(Fn[0]);
        #pragma unroll
        for (int i=1;i<8;i++) rn = nanmax2(rn, fabsf(Fn[i]));
        ws[OFF_TRN+tid] = rn;
        ws[OFF_TFO+tid] = f_obj;

        armijo = f_obj > (foldv + (ALPHA_C*lam)*slopev);
        lq = safe_div((-slopev)*0.5f, (f_obj - foldv) - slopev);
        float lam1v = lam;
        float Af = safe_div(1.0f, lam1v - lam2);
        float i1 = safe_div(1.0f, lam1v*lam1v);
        float i2 = safe_div(1.0f, lam2*lam2);
        float Cc0 = (f_obj - foldv) - lam1v*slopev;
        float Cc1 = (f2v  - foldv) - lam2 *slopev;
        float av = Af*(i1*Cc0 - i2*Cc1);
        float bv = Af*((-(lam2*i1))*Cc0 + (lam1v*i2)*Cc1);
        float disc = bv*bv - (3.0f*av)*slopev;
        float dm = __builtin_isnan(disc) ? disc : fmaxf(disc, 0.0f);  // jnp.maximum NaN-prop
        float sq = sqrtf(dm);
        aNot0 = (av != 0.0f);
        dN    = (disc < 0.0f);
        ble   = (bv <= 0.0f);
        mX = safe_div(-slopev, 2.0f*bv);
        mZ = safe_div(-bv + sq, 3.0f*av);
        mW = safe_div(-slopev, bv + sq);
        nanf = !__builtin_isfinite(f_obj);
        trn = rn;
        ratio = safe_div(rn, rnold);
    }
    #pragma unroll
    for (int o=32;o>=1;o>>=1){
        lq    = nanmin2(lq,    __shfl_xor(lq,    o, 64));
        mX    = nanmin2(mX,    __shfl_xor(mX,    o, 64));
        mZ    = nanmin2(mZ,    __shfl_xor(mZ,    o, 64));
        mW    = nanmin2(mW,    __shfl_xor(mW,    o, 64));
        trn   = nanmax2(trn,   __shfl_xor(trn,   o, 64));
        ratio = nanmax2(ratio, __shfl_xor(ratio, o, 64));
    }
    unsigned long long bArm = __ballot(armijo ? 1 : 0);
    unsigned long long bA0  = __ballot(aNot0  ? 1 : 0);
    unsigned long long bDN  = __ballot(dN     ? 1 : 0);
    unsigned long long bB0  = __ballot(ble    ? 1 : 0);
    unsigned long long bNF  = __ballot(nanf   ? 1 : 0);
    int w = t >> 6;
    if ((t & 63) == 0){
        fred[0][w]=lq; fred[1][w]=mX; fred[2][w]=mZ; fred[3][w]=mW;
        fred[4][w]=trn; fred[5][w]=ratio;
        bbred[w] = (bArm?1u:0u) | (bA0?2u:0u) | (bDN?4u:0u) | (bB0?8u:0u) | (bNF?16u:0u);
    }
    __syncthreads();
    // one atomic per block per slot; each slot on its own 256B line
    if (t < 6){
        float v = fred[t][0];
        bool ismin = (t < 4);
        #pragma unroll
        for (int w2=1; w2<4; ++w2) v = ismin ? nanmin2(v, fred[t][w2]) : nanmax2(v, fred[t][w2]);
        // map t -> slot: 0->lq(+2) 1->mX(+3) 2->mZ(+4) 3->mW(+5) 4->trn(+6) 5->ratio(+7)
        unsigned* p = &r[(size_t)(t + 2)*RSTRIDE];
        if (ismin) atomicMin(p, fkey_min(v));
        else       atomicMax(p, fkey_max(v));
    } else if (t == 6){
        unsigned bm = bbred[0]|bbred[1]|bbred[2]|bbred[3];
        if (bm) atomicOr(&r[(size_t)8*RSTRIDE], bm);
    }
}

// -------- output: y, F, exitflag --------
__global__ __launch_bounds__(256) void kOut(const float* __restrict__ ws, float* __restrict__ out)
{
    const unsigned* R = (const unsigned*)(ws + OFF_R);
    ScalarState S = replay(R, NSTEPS);
    int tid = blockIdx.x*256 + threadIdx.x;
    if (tid < BSZ){
        float v[8];
        ld8(ws+OFF_Y+(size_t)tid*8, v);
        st8(out + (size_t)tid*8, v);
        ld8(ws+OFF_F+(size_t)tid*8, v);
        st8(out + (size_t)BSZ*8 + (size_t)tid*8, v);
    }
    if (tid == 0) out[(size_t)BSZ*16] = (float)S.exitflag;
}

extern "C" void kernel_launch(void* const* d_in, const int* in_sizes, int n_in,
                              void* d_out, int out_size, void* d_ws, size_t ws_size,
                              hipStream_t stream)
{
    const float* y0g = (const float*)d_in[0];
    const float* dtp = (const float*)d_in[1];
    const float* tp  = (const float*)d_in[2];
    const float* Wm  = (const float*)d_in[3];
    const float* Vm  = (const float*)d_in[4];
    float* ws  = (float*)d_ws;
    float* out = (float*)d_out;
    dim3 grid((BSZ + 255)/256), blk(256);

    hipLaunchKernelGGL(kPre, dim3(1), dim3(128), 0, stream, (unsigned*)(ws + OFF_R));
    hipLaunchKernelGGL(kInit, grid, blk, 0, stream, y0g, Wm, Vm, dtp, tp, ws);
    for (int s = 1; s <= NSTEPS; ++s){
        hipLaunchKernelGGL(phaseA, grid, blk, 0, stream, Wm, Vm, dtp, ws, s);
        hipLaunchKernelGGL(phaseB, grid, blk, 0, stream, y0g, Wm, Vm, dtp, tp, ws, s);
    }
    hipLaunchKernelGGL(kOut, grid, blk, 0, stream, ws, out);
}